// Round 1
// baseline (368.123 us; speedup 1.0000x reference)
//
#include <hip/hip_runtime.h>
#include <math.h>

#define B_ 32
#define T_ 512
#define D_ 256
#define TT 32   // timesteps per conv block

// Fused conv1d(K=3,SAME) + bias + relu + layernorm.
// Block: 256 threads. Covers TT=32 timesteps x all 256 output channels.
// Thread layout: o = tid&127 handles channels {o, o+128}; th = tid>>7 picks
// which 16-timestep half. acc[2][16] in registers.
__global__ __launch_bounds__(256) void conv_ln_kernel(
    const float* __restrict__ in,    // (B,T,D)
    const float* __restrict__ w,     // (D_out, D_in, 3)
    const float* __restrict__ bias,
    const float* __restrict__ gamma,
    const float* __restrict__ beta,
    float* __restrict__ out)         // (B,T,D)
{
    __shared__ float xs[D_ * 40];    // transposed tile [d][r], r=0..33, pad to 40
    const int tid = threadIdx.x;
    const int bidx = blockIdx.x;
    const int b  = bidx / (T_ / TT);
    const int t0 = (bidx % (T_ / TT)) * TT;

    // Stage x tile transposed: xs[d*40 + r] = in[b, t0-1+r, d]; zero-pad OOB.
    for (int r = 0; r < TT + 2; ++r) {
        int t = t0 - 1 + r;
        float v = 0.f;
        if (t >= 0 && t < T_) v = in[((size_t)b * T_ + t) * D_ + tid];
        xs[tid * 40 + r] = v;
    }
    __syncthreads();

    const int o  = tid & 127;
    const int th = tid >> 7;

    float acc[2][16];
#pragma unroll
    for (int t = 0; t < 16; ++t) { acc[0][t] = 0.f; acc[1][t] = 0.f; }

    const float* w0p = w + (size_t)o * (D_ * 3);
    const float* w1p = w + (size_t)(o + 128) * (D_ * 3);

    for (int i4 = 0; i4 < D_ / 4; ++i4) {
        // 12 contiguous weights per o-row = 4 input channels x 3 taps
        float4 wa0 = *(const float4*)(w0p + 12 * i4);
        float4 wa1 = *(const float4*)(w0p + 12 * i4 + 4);
        float4 wa2 = *(const float4*)(w0p + 12 * i4 + 8);
        float4 wb0 = *(const float4*)(w1p + 12 * i4);
        float4 wb1 = *(const float4*)(w1p + 12 * i4 + 4);
        float4 wb2 = *(const float4*)(w1p + 12 * i4 + 8);
        float wa[12] = {wa0.x, wa0.y, wa0.z, wa0.w,
                        wa1.x, wa1.y, wa1.z, wa1.w,
                        wa2.x, wa2.y, wa2.z, wa2.w};
        float wb[12] = {wb0.x, wb0.y, wb0.z, wb0.w,
                        wb1.x, wb1.y, wb1.z, wb1.w,
                        wb2.x, wb2.y, wb2.z, wb2.w};
#pragma unroll
        for (int ii = 0; ii < 4; ++ii) {
            int i = 4 * i4 + ii;
            const float* xp = &xs[i * 40 + th * 16];
            float4 x0 = *(const float4*)(xp);
            float4 x1 = *(const float4*)(xp + 4);
            float4 x2 = *(const float4*)(xp + 8);
            float4 x3 = *(const float4*)(xp + 12);
            float2 x4 = *(const float2*)(xp + 16);
            float xr[18] = {x0.x, x0.y, x0.z, x0.w,
                            x1.x, x1.y, x1.z, x1.w,
                            x2.x, x2.y, x2.z, x2.w,
                            x3.x, x3.y, x3.z, x3.w,
                            x4.x, x4.y};
#pragma unroll
            for (int k = 0; k < 3; ++k) {
                float fa = wa[3 * ii + k];
                float fb = wb[3 * ii + k];
#pragma unroll
                for (int t = 0; t < 16; ++t) {
                    acc[0][t] += xr[t + k] * fa;
                    acc[1][t] += xr[t + k] * fb;
                }
            }
        }
    }

    __syncthreads();   // done reading xs; reuse it as y tile [32][256]
    float* ys = xs;
    float ba = bias[o];
    float bb = bias[o + 128];
#pragma unroll
    for (int t = 0; t < 16; ++t) {
        ys[(th * 16 + t) * D_ + o]       = fmaxf(acc[0][t] + ba, 0.f);
        ys[(th * 16 + t) * D_ + o + 128] = fmaxf(acc[1][t] + bb, 0.f);
    }
    __syncthreads();

    // LayerNorm over D for each of the 32 timesteps; wave w handles 8 rows.
    const int wid = tid >> 6, lane = tid & 63;
    float4 gv  = *(const float4*)(gamma + 4 * lane);
    float4 bev = *(const float4*)(beta  + 4 * lane);
    for (int tt = 0; tt < 8; ++tt) {
        int t = wid * 8 + tt;
        float4 v = *(const float4*)(&ys[t * D_ + 4 * lane]);
        float s  = v.x + v.y + v.z + v.w;
        float s2 = v.x * v.x + v.y * v.y + v.z * v.z + v.w * v.w;
#pragma unroll
        for (int off = 32; off >= 1; off >>= 1) {
            s  += __shfl_xor(s,  off);
            s2 += __shfl_xor(s2, off);
        }
        float m   = s  * (1.f / D_);
        float var = s2 * (1.f / D_) - m * m;
        float rs  = rsqrtf(var + 1e-5f);
        float4 r;
        r.x = (v.x - m) * rs * gv.x + bev.x;
        r.y = (v.y - m) * rs * gv.y + bev.y;
        r.z = (v.z - m) * rs * gv.z + bev.z;
        r.w = (v.w - m) * rs * gv.w + bev.w;
        *(float4*)(&out[((size_t)b * T_ + t0 + t) * D_ + 4 * lane]) = r;
    }
}

// pred[b,t] = h2[b,t,:] . wl + bl   — one wave per (b,t)
__global__ __launch_bounds__(256) void linear_kernel(
    const float* __restrict__ h, const float* __restrict__ wl,
    const float* __restrict__ bl, float* __restrict__ pred)
{
    int tid = threadIdx.x, wid = tid >> 6, lane = tid & 63;
    int bt = blockIdx.x * 4 + wid;
    float4 v  = *(const float4*)(&h[(size_t)bt * D_ + 4 * lane]);
    float4 wv = *(const float4*)(&wl[4 * lane]);
    float s = v.x * wv.x + v.y * wv.y + v.z * wv.z + v.w * wv.w;
#pragma unroll
    for (int off = 32; off >= 1; off >>= 1) s += __shfl_xor(s, off);
    if (lane == 0) pred[bt] = s + bl[0];
}

// Per-batch inclusive cumsum of durations (ALPHA=1.0 -> dur == target).
__global__ __launch_bounds__(512) void scan_kernel(
    const int* __restrict__ td, int* __restrict__ ends)
{
    __shared__ int s[T_];
    int b = blockIdx.x, t = threadIdx.x;
    s[t] = td[b * T_ + t];
    __syncthreads();
    for (int off = 1; off < T_; off <<= 1) {
        int add = (t >= off) ? s[t - off] : 0;
        __syncthreads();
        s[t] += add;
        __syncthreads();
    }
    ends[b * T_ + t] = s[t];
}

// out[b,m,:] = x[b, t(m), :] via binary search over ends; zeros past lens[b].
__global__ __launch_bounds__(256) void gather_kernel(
    const float* __restrict__ x, const int* __restrict__ ends,
    float* __restrict__ out, int maxLen)
{
    int tid = threadIdx.x, wid = tid >> 6, lane = tid & 63;
    int idx = blockIdx.x * 4 + wid;
    int b = idx / maxLen, m = idx % maxLen;
    if (b >= B_) return;
    const int* e = &ends[b * T_];
    float4 r = make_float4(0.f, 0.f, 0.f, 0.f);
    if (m < e[T_ - 1]) {
        int lo = 0, hi = T_ - 1;   // first t with ends[t] > m
        while (lo < hi) {
            int mid = (lo + hi) >> 1;
            if (e[mid] > m) hi = mid; else lo = mid + 1;
        }
        r = *(const float4*)(&x[((size_t)b * T_ + lo) * D_ + 4 * lane]);
    }
    *(float4*)(&out[((size_t)b * maxLen + m) * D_ + 4 * lane]) = r;
}

extern "C" void kernel_launch(void* const* d_in, const int* in_sizes, int n_in,
                              void* d_out, int out_size, void* d_ws, size_t ws_size,
                              hipStream_t stream) {
    const float* x   = (const float*)d_in[0];
    const int*   td  = (const int*)d_in[1];
    const float* w1  = (const float*)d_in[2];
    const float* b1  = (const float*)d_in[3];
    const float* g1  = (const float*)d_in[4];
    const float* be1 = (const float*)d_in[5];
    const float* w2  = (const float*)d_in[6];
    const float* b2  = (const float*)d_in[7];
    const float* g2  = (const float*)d_in[8];
    const float* be2 = (const float*)d_in[9];
    const float* wl  = (const float*)d_in[10];
    const float* bl  = (const float*)d_in[11];
    float* outp = (float*)d_out;

    const size_t BTD = (size_t)B_ * T_ * D_;
    const int BT = B_ * T_;
    const int maxLen = (out_size - BT) / (B_ * D_);
    float* predp = outp + (size_t)B_ * maxLen * D_;

    float *h1, *h2;
    int* endsp;
    size_t need = 2 * BTD * sizeof(float) + (size_t)BT * sizeof(int);
    if (ws_size >= need) {
        h1 = (float*)d_ws;
        h2 = h1 + BTD;
        endsp = (int*)(h2 + BTD);
    } else {
        // Park hidden activations in the (larger) out region of d_out; they
        // are fully consumed before gather_kernel overwrites that region.
        h1 = outp;
        h2 = outp + BTD;
        endsp = (int*)d_ws;
    }

    conv_ln_kernel<<<B_ * (T_ / TT), 256, 0, stream>>>(x,  w1, b1, g1, be1, h1);
    conv_ln_kernel<<<B_ * (T_ / TT), 256, 0, stream>>>(h1, w2, b2, g2, be2, h2);
    linear_kernel<<<BT / 4, 256, 0, stream>>>(h2, wl, bl, predp);
    scan_kernel<<<B_, T_, 0, stream>>>(td, endsp);
    gather_kernel<<<(B_ * maxLen + 3) / 4, 256, 0, stream>>>(x, endsp, outp, maxLen);
}

// Round 2
// 91.897 us; speedup vs baseline: 4.0058x; 4.0058x over previous
//
#include <hip/hip_runtime.h>
#include <math.h>

#define B_ 32
#define T_ 512
#define D_ 256
#define TP_ 514              // padded T: one zero row each side
#define KTOT 768             // 3 taps x 256 channels
#define BK 32
#define NSTEP 24             // KTOT / BK
#define TILE_M 64

typedef __bf16 bf16x8 __attribute__((ext_vector_type(8)));
typedef __bf16 bf16x4 __attribute__((ext_vector_type(4)));
typedef float  f32x4  __attribute__((ext_vector_type(4)));

__device__ __forceinline__ void gload16(const void* g, void* l) {
    __builtin_amdgcn_global_load_lds(
        (const __attribute__((address_space(1))) unsigned int*)g,
        (__attribute__((address_space(3))) unsigned int*)l, 16, 0, 0);
}

// One conv layer as bf16 GEMM + fused bias/ReLU/LayerNorm.
//   y[bt, n] = sum_{k,i} Xpad[b, t+k, i] * W[n, i, k]
// A-tile and B-tile are both [row][32] bf16 in LDS (64B rows), XOR-swizzled
// (cb ^= row&3, an involution) on both the global_load_lds SOURCE and the
// ds_read side so fragment reads are ~2-way-conflict (free).
__global__ __launch_bounds__(256) void gemm_conv_ln_kernel(
    const __bf16* __restrict__ xpad,   // (B, 514, 256)
    const __bf16* __restrict__ bmat,   // (256, 768): bmat[n][k*256+i] = W[n,i,k]
    const float* __restrict__ bias,
    const float* __restrict__ gamma,
    const float* __restrict__ beta,
    __bf16* __restrict__ dst,          // padded (B,514,256) if dstPad else (B,512,256)
    int dstPad)
{
    __shared__ __align__(16) unsigned char lds[2 * 20480 + 64 * 268 * 4];
    const int tid  = threadIdx.x;
    const int lane = tid & 63;
    const int wid  = tid >> 6;
    const int m0 = blockIdx.x * TILE_M;
    const int bb = m0 >> 9;            // batch (64 | 512 -> tile within one batch)
    const int t0 = m0 & 511;

    f32x4 acc[4][4];
#pragma unroll
    for (int mf = 0; mf < 4; ++mf)
#pragma unroll
        for (int nf = 0; nf < 4; ++nf)
            acc[mf][nf] = (f32x4){0.f, 0.f, 0.f, 0.f};

    auto STAGE = [&](int kstep, int half) {
        const int k  = kstep >> 3;          // tap 0..2
        const int i0 = (kstep & 7) * BK;    // channel block
        unsigned char* buf = lds + half * 20480;
        {   // A tile: 64 rows x 32 bf16 (4KB, chunk = tid)
            int r = tid >> 2, cb = tid & 3, scb = cb ^ (r & 3);
            const __bf16* src = xpad + ((size_t)(bb * TP_ + t0 + r + k)) * D_ + i0 + scb * 8;
            gload16(src, buf + tid * 16);
        }
#pragma unroll
        for (int p = 1; p < 5; ++p) {       // B tile: 256 rows x 32 bf16 (16KB)
            int c = p * 256 + tid - 256;    // 0..1023
            int n = c >> 2, cb = c & 3, scb = cb ^ (n & 3);
            const __bf16* src = bmat + (size_t)n * KTOT + kstep * BK + scb * 8;
            gload16(src, buf + 4096 + c * 16);
        }
    };

    auto COMPUTE = [&](int half) {
        unsigned char* Ab = lds + half * 20480;
        unsigned char* Bb = Ab + 4096;
        const int swz = ((lane >> 4) ^ (lane & 3)) * 16;   // row&3 == lane&3 for all frags
        const int rA  = lane & 15;
        bf16x8 a[4], bv[4];
#pragma unroll
        for (int mf = 0; mf < 4; ++mf)
            a[mf] = *(const bf16x8*)(Ab + (mf * 16 + rA) * 64 + swz);
#pragma unroll
        for (int nf = 0; nf < 4; ++nf)
            bv[nf] = *(const bf16x8*)(Bb + (wid * 64 + nf * 16 + rA) * 64 + swz);
#pragma unroll
        for (int mf = 0; mf < 4; ++mf)
#pragma unroll
            for (int nf = 0; nf < 4; ++nf)
                acc[mf][nf] = __builtin_amdgcn_mfma_f32_16x16x32_bf16(
                    a[mf], bv[nf], acc[mf][nf], 0, 0, 0);
    };

    STAGE(0, 0);
    int half = 0;
    for (int t = 0; t < NSTEP; ++t) {
        __syncthreads();                       // staged buf[half] ready (vmcnt drain)
        if (t + 1 < NSTEP) STAGE(t + 1, half ^ 1);
        COMPUTE(half);
        half ^= 1;
    }

    // ---- epilogue: bias + relu -> y LDS (f32), then rowwise LN over 256 ----
    float* y = (float*)(lds + 40960);          // [64][268] f32, pad kills conflicts
    float bsv[4];
#pragma unroll
    for (int nf = 0; nf < 4; ++nf) bsv[nf] = bias[wid * 64 + nf * 16 + (lane & 15)];
    const int rg = lane >> 4;
#pragma unroll
    for (int mf = 0; mf < 4; ++mf)
#pragma unroll
        for (int nf = 0; nf < 4; ++nf)
#pragma unroll
            for (int r = 0; r < 4; ++r) {
                int row = mf * 16 + rg * 4 + r;
                int col = wid * 64 + nf * 16 + (lane & 15);
                y[row * 268 + col] = fmaxf(acc[mf][nf][r] + bsv[nf], 0.f);
            }
    __syncthreads();

    const int rr = wid * 16 + (lane >> 2);     // row handled by this lane group
    const int c0 = (lane & 3) * 64;            // 64-col slice per lane
    float s = 0.f, s2 = 0.f;
#pragma unroll
    for (int j = 0; j < 16; ++j) {
        f32x4 v = *(f32x4*)(y + rr * 268 + c0 + 4 * j);
        s  += v[0] + v[1] + v[2] + v[3];
        s2 += v[0] * v[0] + v[1] * v[1] + v[2] * v[2] + v[3] * v[3];
    }
    s  += __shfl_xor(s, 1);  s  += __shfl_xor(s, 2);
    s2 += __shfl_xor(s2, 1); s2 += __shfl_xor(s2, 2);
    const float mean = s * (1.f / 256.f);
    const float var  = s2 * (1.f / 256.f) - mean * mean;
    const float rstd = rsqrtf(var + 1e-5f);

    const int tt = t0 + rr;
    const size_t drow = dstPad ? ((size_t)bb * TP_ + 1 + tt) : ((size_t)bb * T_ + tt);
    __bf16* dp = dst + drow * D_ + c0;
#pragma unroll
    for (int j = 0; j < 16; ++j) {
        f32x4 v  = *(f32x4*)(y + rr * 268 + c0 + 4 * j);
        f32x4 g  = *(const f32x4*)(gamma + c0 + 4 * j);
        f32x4 be = *(const f32x4*)(beta  + c0 + 4 * j);
        bf16x4 o;
#pragma unroll
        for (int e = 0; e < 4; ++e)
            o[e] = (__bf16)((v[e] - mean) * rstd * g[e] + be[e]);
        *(bf16x4*)(dp + 4 * j) = o;
    }
}

// xpad (zero-padded bf16 x), BmatT for both convs, zero pad rows of h1pad.
__global__ __launch_bounds__(256) void prep_kernel(
    const float* __restrict__ x, const float* __restrict__ w1,
    const float* __restrict__ w2,
    __bf16* __restrict__ xpad, __bf16* __restrict__ bm1,
    __bf16* __restrict__ bm2, __bf16* __restrict__ h1pad)
{
    const int NX = B_ * TP_ * D_;      // 4,210,688
    const int NW = D_ * KTOT;          // 196,608
    const int NZ = B_ * 2 * D_;        // 16,384
    const int total = NX + 2 * NW + NZ;
    for (int idx = blockIdx.x * blockDim.x + threadIdx.x; idx < total;
         idx += gridDim.x * blockDim.x) {
        if (idx < NX) {
            int b = idx / (TP_ * D_);
            int rem = idx - b * (TP_ * D_);
            int r = rem >> 8, d = rem & 255;
            int t = r - 1;
            float v = ((unsigned)t < (unsigned)T_) ? x[((size_t)b * T_ + t) * D_ + d] : 0.f;
            xpad[idx] = (__bf16)v;
        } else if (idx < NX + 2 * NW) {
            int j = idx - NX;
            const float* ws = w1;
            __bf16* bm = bm1;
            if (j >= NW) { j -= NW; ws = w2; bm = bm2; }
            int n = j / KTOT;
            int kap = j - n * KTOT;
            int k = kap >> 8, i = kap & 255;
            bm[j] = (__bf16)ws[(n * D_ + i) * 3 + k];
        } else {
            int j = idx - NX - 2 * NW;
            int b = j >> 9, q = (j >> 8) & 1, d = j & 255;
            h1pad[((size_t)b * TP_ + (q ? TP_ - 1 : 0)) * D_ + d] = (__bf16)0.f;
        }
    }
}

// pred[b,t] = h2[b,t,:] . wl + bl   — one wave per (b,t), bf16 h2
__global__ __launch_bounds__(256) void linear_kernel(
    const __bf16* __restrict__ h, const float* __restrict__ wl,
    const float* __restrict__ bl, float* __restrict__ pred)
{
    int tid = threadIdx.x, wd = tid >> 6, lane = tid & 63;
    int bt = blockIdx.x * 4 + wd;
    bf16x4 v = *(const bf16x4*)(&h[(size_t)bt * D_ + 4 * lane]);
    f32x4 wv = *(const f32x4*)(&wl[4 * lane]);
    float s = (float)v[0] * wv[0] + (float)v[1] * wv[1] +
              (float)v[2] * wv[2] + (float)v[3] * wv[3];
#pragma unroll
    for (int off = 32; off >= 1; off >>= 1) s += __shfl_xor(s, off);
    if (lane == 0) pred[bt] = s + bl[0];
}

// Per-batch inclusive cumsum of durations (ALPHA=1.0 -> dur == target).
__global__ __launch_bounds__(512) void scan_kernel(
    const int* __restrict__ td, int* __restrict__ ends)
{
    __shared__ int s[T_];
    int b = blockIdx.x, t = threadIdx.x;
    s[t] = td[b * T_ + t];
    __syncthreads();
    for (int off = 1; off < T_; off <<= 1) {
        int add = (t >= off) ? s[t - off] : 0;
        __syncthreads();
        s[t] += add;
        __syncthreads();
    }
    ends[b * T_ + t] = s[t];
}

// out[b,m,:] = x[b, t(m), :] via binary search over ends; zeros past lens[b].
__global__ __launch_bounds__(256) void gather_kernel(
    const float* __restrict__ x, const int* __restrict__ ends,
    float* __restrict__ out, int maxLen)
{
    int tid = threadIdx.x, wd = tid >> 6, lane = tid & 63;
    int idx = blockIdx.x * 4 + wd;
    int b = idx / maxLen, m = idx % maxLen;
    if (b >= B_) return;
    const int* e = &ends[b * T_];
    float4 r = make_float4(0.f, 0.f, 0.f, 0.f);
    if (m < e[T_ - 1]) {
        int lo = 0, hi = T_ - 1;   // first t with ends[t] > m
        while (lo < hi) {
            int mid = (lo + hi) >> 1;
            if (e[mid] > m) hi = mid; else lo = mid + 1;
        }
        r = *(const float4*)(&x[((size_t)b * T_ + lo) * D_ + 4 * lane]);
    }
    *(float4*)(&out[((size_t)b * maxLen + m) * D_ + 4 * lane]) = r;
}

extern "C" void kernel_launch(void* const* d_in, const int* in_sizes, int n_in,
                              void* d_out, int out_size, void* d_ws, size_t ws_size,
                              hipStream_t stream) {
    const float* x   = (const float*)d_in[0];
    const int*   td  = (const int*)d_in[1];
    const float* w1  = (const float*)d_in[2];
    const float* b1  = (const float*)d_in[3];
    const float* g1  = (const float*)d_in[4];
    const float* be1 = (const float*)d_in[5];
    const float* w2  = (const float*)d_in[6];
    const float* b2  = (const float*)d_in[7];
    const float* g2  = (const float*)d_in[8];
    const float* be2 = (const float*)d_in[9];
    const float* wl  = (const float*)d_in[10];
    const float* bl  = (const float*)d_in[11];
    float* outp = (float*)d_out;

    const int BT = B_ * T_;
    const int maxLen = (out_size - BT) / (B_ * D_);
    float* predp = outp + (size_t)B_ * maxLen * D_;

    const size_t SZ_XPAD = (size_t)B_ * TP_ * D_ * 2;   // 8,421,376
    const size_t SZ_H1   = SZ_XPAD;
    const size_t SZ_H2   = (size_t)BT * D_ * 2;         // 8,388,608
    const size_t SZ_BM   = (size_t)D_ * KTOT * 2;       // 393,216
    const size_t SZ_ENDS = 65536;
    const size_t need = SZ_ENDS + SZ_XPAD + SZ_H1 + SZ_H2 + 2 * SZ_BM;

    int* endsp = (int*)d_ws;                            // always in ws (small)
    char* base;
    if (ws_size >= need) base = (char*)d_ws + SZ_ENDS;
    else                 base = (char*)d_out;           // park in out region; gather
                                                        // (launched last) overwrites it
    __bf16* xpadp  = (__bf16*)(base);
    __bf16* h1padp = (__bf16*)(base + SZ_XPAD);
    __bf16* h2p    = (__bf16*)(base + SZ_XPAD + SZ_H1);
    __bf16* bm1p   = (__bf16*)(base + SZ_XPAD + SZ_H1 + SZ_H2);
    __bf16* bm2p   = (__bf16*)(base + SZ_XPAD + SZ_H1 + SZ_H2 + SZ_BM);

    prep_kernel<<<2048, 256, 0, stream>>>(x, w1, w2, xpadp, bm1p, bm2p, h1padp);
    gemm_conv_ln_kernel<<<BT / TILE_M, 256, 0, stream>>>(xpadp, bm1p, b1, g1, be1, h1padp, 1);
    gemm_conv_ln_kernel<<<BT / TILE_M, 256, 0, stream>>>(h1padp, bm2p, b2, g2, be2, h2p, 0);
    linear_kernel<<<BT / 4, 256, 0, stream>>>(h2p, wl, bl, predp);
    scan_kernel<<<B_, T_, 0, stream>>>(td, endsp);
    gather_kernel<<<(B_ * maxLen + 3) / 4, 256, 0, stream>>>(x, endsp, outp, maxLen);
}